// Round 1
// baseline (264.725 us; speedup 1.0000x reference)
//
#include <hip/hip_runtime.h>

// Spatially-varying 19x19 blur, reflect padding 9.
// out[b,c,i,j] = (1/361) * sum_{u,v} xpad[b,c,i+u,j+v] * kernel[b,u*19+v,i,j]
// Shapes: x[2,3,256,256] f32, kernel[2,361,256,256] f32, out[2,3,256,256] f32.
//
// Memory-bound on the 189 MB kernel tensor (read once, no reuse).
// Structure: each thread owns 2 consecutive j pixels (float2 kernel loads),
// kernel taps for one u-row (19 float2) are prefetched into a register
// ping-pong buffer one full row ahead of the FMAs -> >=19 dwordx2 loads
// (9.7 KB/wave) in flight during every compute phase. LDS x-window read as
// ds_read_b64 once per (u,c) instead of per-tap scalar reads.

#define LW     19
#define PAD    9
#define K2     361
#define HH     256
#define WW     256
#define CC     3
#define HW     (HH * WW)
#define TPX    2                    // pixels per thread (float2)
#define TX     64                   // threads in x
#define TY     4                    // threads in y
#define TILE_W (TX * TPX)           // 128
#define TILE_H TY                   // 4
#define SM_W   (TILE_W + LW - 1)    // 146
#define SM_H   (TILE_H + LW - 1)    // 22

// Load one u-row of kernel taps (19 float2) into a register buffer.
#define PREFETCH_ROW(u_, buf_)                                              \
  {                                                                         \
    _Pragma("unroll")                                                       \
    for (int v = 0; v < LW; ++v)                                            \
      (buf_)[v] = *(const float2*)(kp + (size_t)((u_) * LW + v) * HW);      \
  }

// FMA one u-row: read 20-float x-window per channel from LDS (10 x b64),
// multiply against the register-resident kernel row.
#define COMPUTE_ROW(u_, buf_)                                               \
  {                                                                         \
    _Pragma("unroll")                                                       \
    for (int c = 0; c < CC; ++c) {                                          \
      const float* wp = &tile[c][ty + (u_)][tx * TPX];                      \
      float2 w[10];                                                         \
      _Pragma("unroll")                                                     \
      for (int q = 0; q < 10; ++q) w[q] = *(const float2*)(wp + q * 2);     \
      _Pragma("unroll")                                                     \
      for (int v = 0; v < LW; ++v) {                                        \
        const float xe = ((v) & 1) ? w[(v) >> 1].y : w[(v) >> 1].x;         \
        const float xo = (((v) + 1) & 1) ? w[((v) + 1) >> 1].y              \
                                         : w[((v) + 1) >> 1].x;             \
        acc[c].x = fmaf(xe, (buf_)[v].x, acc[c].x);                         \
        acc[c].y = fmaf(xo, (buf_)[v].y, acc[c].y);                         \
      }                                                                     \
    }                                                                       \
  }

__global__ __launch_bounds__(256)
void svblur_kernel(const float* __restrict__ x,
                   const float* __restrict__ ker,
                   float* __restrict__ out) {
    __shared__ float tile[CC][SM_H][SM_W];   // 3*22*146*4 = 38544 B

    const int tx  = threadIdx.x;             // 0..63
    const int ty  = threadIdx.y;             // 0..3
    const int tid = ty * TX + tx;            // 0..255
    const int j0  = blockIdx.x * TILE_W;
    const int i0  = blockIdx.y * TILE_H;
    const int b   = blockIdx.z;

    const int i  = i0 + ty;
    const int jj = j0 + tx * TPX;
    const float* kp = ker + ((size_t)b * K2 * HH + i) * WW + jj;

    // Issue row-0 kernel prefetch FIRST so it flies under the LDS staging.
    float2 bufA[LW], bufB[LW];
    PREFETCH_ROW(0, bufA);

    // ---- stage reflect-padded input tile into LDS ----
    const float* xb = x + (size_t)b * CC * HW;
    for (int idx = tid; idx < CC * SM_H * SM_W; idx += TX * TY) {
        int c  = idx / (SM_H * SM_W);
        int rm = idx - c * (SM_H * SM_W);
        int r  = rm / SM_W;
        int cc = rm - r * SM_W;
        int gr = i0 + r - PAD;
        gr = gr < 0 ? -gr : (gr >= HH ? 2 * HH - 2 - gr : gr);
        int gc = j0 + cc - PAD;
        gc = gc < 0 ? -gc : (gc >= WW ? 2 * WW - 2 - gc : gc);
        ((float*)tile)[idx] = xb[((size_t)c * HH + gr) * WW + gc];
    }
    __syncthreads();

    float2 acc[CC] = {};

    // Software-pipelined u-loop: prefetch row u+1 while computing row u.
    #pragma unroll
    for (int u = 0; u < LW - 1; u += 2) {    // u = 0,2,...,16
        PREFETCH_ROW(u + 1, bufB);
        COMPUTE_ROW(u, bufA);
        PREFETCH_ROW(u + 2, bufA);           // u+2 <= 18 always
        COMPUTE_ROW(u + 1, bufB);
    }
    COMPUTE_ROW(LW - 1, bufA);               // u = 18 (prefetched at u=16)

    const float s = 1.0f / (float)K2;
    float* op = out + (((size_t)b * CC) * HH + i) * WW + jj;
    #pragma unroll
    for (int c = 0; c < CC; ++c) {
        float2 r;
        r.x = acc[c].x * s;
        r.y = acc[c].y * s;
        *(float2*)(op + (size_t)c * HW) = r;
    }
}

extern "C" void kernel_launch(void* const* d_in, const int* in_sizes, int n_in,
                              void* d_out, int out_size, void* d_ws, size_t ws_size,
                              hipStream_t stream) {
    const float* x   = (const float*)d_in[0];   // [2,3,256,256]
    const float* ker = (const float*)d_in[1];   // [2,361,256,256]
    float* out       = (float*)d_out;           // [2,3,256,256]

    dim3 grid(WW / TILE_W, HH / TILE_H, 2);     // (2, 64, 2) = 256 blocks
    dim3 block(TX, TY, 1);                      // 256 threads
    svblur_kernel<<<grid, block, 0, stream>>>(x, ker, out);
}

// Round 2
// 264.327 us; speedup vs baseline: 1.0015x; 1.0015x over previous
//
#include <hip/hip_runtime.h>

// Spatially-varying 19x19 blur, reflect padding 9 — k-split variant.
// out[b,c,i,j] = (1/361) * sum_{u,v} xpad[b,c,i+u,j+v] * kernel[b,u*19+v,i,j]
// x[2,3,256,256] f32, kernel[2,361,256,256] f32, out[2,3,256,256] f32.
//
// Memory-bound on the 189 MB kernel tensor (read once). The tap loop is split
// into 4 u-bands (5/5/5/4 rows) handled by separate blocks -> 1024 blocks,
// 4 blocks/CU, ~16 waves/CU, ~4x in-flight HBM reads vs the previous 1
// block/CU version. Partial sums land in d_ws; a small second kernel reduces
// the 4 bands and applies the 1/361 scale (deterministic, no atomics).

#define LW     19
#define PAD    9
#define K2     361
#define HH     256
#define WW     256
#define CC     3
#define HW     (HH * WW)
#define TPX    2                    // pixels per thread (float2)
#define TX     64
#define TY     4
#define TILE_W (TX * TPX)           // 128
#define TILE_H TY                   // 4
#define SM_W   (TILE_W + LW - 1)    // 146
#define NSPLIT 4
#define NU_MAX 5
#define SM_H   (TILE_H + NU_MAX - 1) // 8

// Load taps v=0..18 of band-row du_ into a float2 register buffer.
#define PREFETCH_ROW(du_, buf_)                                             \
  {                                                                         \
    const float* kq = kp + (size_t)((du_) * LW) * HW;                       \
    _Pragma("unroll")                                                       \
    for (int v = 0; v < LW; ++v)                                            \
      (buf_)[v] = *(const float2*)(kq + (size_t)v * HW);                    \
  }

// FMA one band-row against the register-resident tap row.
#define COMPUTE_ROW(du_, buf_)                                              \
  {                                                                         \
    _Pragma("unroll")                                                       \
    for (int c = 0; c < CC; ++c) {                                          \
      const float* wp = &tile[c][ty + (du_)][tx * TPX];                     \
      float2 w[10];                                                         \
      _Pragma("unroll")                                                     \
      for (int q = 0; q < 10; ++q) w[q] = *(const float2*)(wp + q * 2);     \
      _Pragma("unroll")                                                     \
      for (int v = 0; v < LW; ++v) {                                        \
        const float xe = ((v) & 1) ? w[(v) >> 1].y : w[(v) >> 1].x;         \
        const float xo = (((v) + 1) & 1) ? w[((v) + 1) >> 1].y              \
                                         : w[((v) + 1) >> 1].x;             \
        acc[c].x = fmaf(xe, (buf_)[v].x, acc[c].x);                         \
        acc[c].y = fmaf(xo, (buf_)[v].y, acc[c].y);                         \
      }                                                                     \
    }                                                                       \
  }

__global__ __launch_bounds__(256)
void svblur_part(const float* __restrict__ x,
                 const float* __restrict__ ker,
                 float* __restrict__ part) {
    __shared__ float tile[CC][SM_H][SM_W];   // 3*8*146*4 = 14016 B

    const int tx  = threadIdx.x;             // 0..63
    const int ty  = threadIdx.y;             // 0..3
    const int tid = ty * TX + tx;
    const int j0  = blockIdx.x * TILE_W;
    const int i0  = blockIdx.y * TILE_H;
    const int zz  = blockIdx.z;              // b*NSPLIT + s
    const int b   = zz >> 2;
    const int s   = zz & 3;
    const int u0  = s * NU_MAX;              // 0,5,10,15
    const int nuM1 = (s == 3) ? 3 : 4;       // rows in band - 1

    const int i  = i0 + ty;
    const int jj = j0 + tx * TPX;
    const float* kp = ker + (((size_t)b * K2 + u0 * LW) * HH + i) * WW + jj;

    // Row-0 prefetch first so it flies under the LDS staging.
    float2 bufA[LW], bufB[LW];
    PREFETCH_ROW(0, bufA);

    // Stage x rows (i0 + u0 - PAD) .. (+ SM_H - 1), reflect-padded.
    const float* xb = x + (size_t)b * CC * HW;
    for (int idx = tid; idx < CC * SM_H * SM_W; idx += TX * TY) {
        int c  = idx / (SM_H * SM_W);
        int rm = idx - c * (SM_H * SM_W);
        int r  = rm / SM_W;
        int cc = rm - r * SM_W;
        int gr = i0 + u0 + r - PAD;
        gr = gr < 0 ? -gr : (gr >= HH ? 2 * HH - 2 - gr : gr);
        int gc = j0 + cc - PAD;
        gc = gc < 0 ? -gc : (gc >= WW ? 2 * WW - 2 - gc : gc);
        ((float*)tile)[idx] = xb[((size_t)c * HH + gr) * WW + gc];
    }
    __syncthreads();

    float2 acc[CC] = {};

    // Ping-pong over the (up to) 5 band rows; prefetch clamped so the
    // 4-row band never reads plane k >= 361.
    PREFETCH_ROW(1, bufB);
    COMPUTE_ROW(0, bufA);
    PREFETCH_ROW(2, bufA);
    COMPUTE_ROW(1, bufB);
    PREFETCH_ROW(3, bufB);
    COMPUTE_ROW(2, bufA);
    PREFETCH_ROW(((4 < nuM1 ? 4 : nuM1)), bufA);
    COMPUTE_ROW(3, bufB);
    if (nuM1 == 4) { COMPUTE_ROW(4, bufA); }

    // Unscaled partial write: part[zz][c][i][j]
    float* pp = part + ((size_t)zz * CC) * HW + (size_t)i * WW + jj;
    #pragma unroll
    for (int c = 0; c < CC; ++c)
        *(float2*)(pp + (size_t)c * HW) = acc[c];
}

__global__ __launch_bounds__(256)
void svblur_reduce(const float* __restrict__ part, float* __restrict__ out) {
    const int PLANE4 = CC * HW / 4;                   // 49152 float4 per (b,s)
    const int gid = blockIdx.x * 256 + threadIdx.x;   // 0..98303
    const int b = gid / PLANE4;
    const int within = gid - b * PLANE4;
    const float4* p4 = (const float4*)part;
    float4 s0 = p4[(size_t)(b * NSPLIT + 0) * PLANE4 + within];
    float4 s1 = p4[(size_t)(b * NSPLIT + 1) * PLANE4 + within];
    float4 s2 = p4[(size_t)(b * NSPLIT + 2) * PLANE4 + within];
    float4 s3 = p4[(size_t)(b * NSPLIT + 3) * PLANE4 + within];
    const float sc = 1.0f / (float)K2;
    float4 r;
    r.x = (s0.x + s1.x + s2.x + s3.x) * sc;
    r.y = (s0.y + s1.y + s2.y + s3.y) * sc;
    r.z = (s0.z + s1.z + s2.z + s3.z) * sc;
    r.w = (s0.w + s1.w + s2.w + s3.w) * sc;
    ((float4*)out)[gid] = r;
}

extern "C" void kernel_launch(void* const* d_in, const int* in_sizes, int n_in,
                              void* d_out, int out_size, void* d_ws, size_t ws_size,
                              hipStream_t stream) {
    const float* x   = (const float*)d_in[0];   // [2,3,256,256]
    const float* ker = (const float*)d_in[1];   // [2,361,256,256]
    float* out       = (float*)d_out;           // [2,3,256,256]
    float* part      = (float*)d_ws;            // 8 * 3 * 256 * 256 * 4 = 6 MB

    dim3 g1(WW / TILE_W, HH / TILE_H, 2 * NSPLIT);  // (2, 64, 8) = 1024 blocks
    dim3 b1(TX, TY, 1);                             // 256 threads
    svblur_part<<<g1, b1, 0, stream>>>(x, ker, part);

    dim3 g2((2 * CC * HW / 4) / 256, 1, 1);         // 384 blocks
    dim3 b2(256, 1, 1);
    svblur_reduce<<<g2, b2, 0, stream>>>(part, out);
}